// Round 5
// baseline (501.088 us; speedup 1.0000x reference)
//
#include <hip/hip_runtime.h>
#include <stdint.h>
#include <stddef.h>

// Problem constants
constexpr int B_ = 16, N_ = 8, C_ = 3, H_ = 48, W_ = 48, K_ = 5, NK_ = 4;
constexpr int HW_ = H_ * W_;            // 2304
constexpr int IMGS_ = B_ * N_;          // 128
constexpr int PW_ = W_ + 4;             // 52 (padded width)
constexpr int PH_ = H_ + 4;             // 52
constexpr int PHW_ = PH_ * PW_;         // 2704

typedef float f32x4 __attribute__((ext_vector_type(4)));

// Kernel 1: padded channel-sum of frames: cs[img][52][52] (fp32), zero border.
__global__ void kcs(const float* __restrict__ frames, float* __restrict__ cs) {
    int id = blockIdx.x * blockDim.x + threadIdx.x;
    if (id >= IMGS_ * PHW_) return;
    int img = id / PHW_;
    int rem = id - img * PHW_;
    int ph = rem / PW_;
    int pw = rem - ph * PW_;
    int h = ph - 2, w = pw - 2;
    float s = 0.f;
    if ((unsigned)h < (unsigned)H_ && (unsigned)w < (unsigned)W_) {
        const float* f = frames + (size_t)img * (C_ * HW_) + h * W_ + w;
        s = f[0] + f[HW_] + f[2 * HW_];
    }
    cs[id] = s;
}

// Kernel 2: partial conv, CONTIGUOUS streaming. Block = (img, g, seg).
// seg = k/5 band (di == seg for all 5 k's in the band), so the block's 15
// planes [seg*15, seg*15+15) of core[img][g*75 + ...] are one contiguous
// 138 KB range, streamed fully coalesced by 192 threads x 3 quads.
// Writes partial t[img][g][seg][c][p] = sum_{k in band} core * fs.
__global__ __launch_bounds__(192) void kpart(const float* __restrict__ core,
                                             const float* __restrict__ cs,
                                             float* __restrict__ partial) {
    int b = blockIdx.x;
    int img = b / 20;
    int r = b - img * 20;
    int g = r / 5;
    int seg = r - g * 5;      // = di for every k in this block
    int t = threadIdx.x;

    // 3 quads per thread: q = t + 192*s, pixel base p = q*4
    int q0 = t, q1 = t + 192, q2 = t + 384;
    int h0 = q0 / 12, w00 = (q0 % 12) * 4;
    int h1 = q1 / 12, w01 = (q1 % 12) * 4;
    int h2 = q2 / 12, w02 = (q2 % 12) * 4;

    // fs[s][0..7] = cs_pad[img][h_s + seg][w0_s .. w0_s+7]  (row fixed: di=seg)
    float fs[3][8];
    {
        const float* ci = cs + (size_t)img * PHW_;
        const float* r0 = ci + (h0 + seg) * PW_ + w00;
        const float* r1 = ci + (h1 + seg) * PW_ + w01;
        const float* r2 = ci + (h2 + seg) * PW_ + w02;
        f32x4 a0 = *(const f32x4*)r0, b0 = *(const f32x4*)(r0 + 4);
        f32x4 a1 = *(const f32x4*)r1, b1 = *(const f32x4*)(r1 + 4);
        f32x4 a2 = *(const f32x4*)r2, b2 = *(const f32x4*)(r2 + 4);
#pragma unroll
        for (int j = 0; j < 4; ++j) {
            fs[0][j] = a0[j]; fs[0][j + 4] = b0[j];
            fs[1][j] = a1[j]; fs[1][j + 4] = b1[j];
            fs[2][j] = a2[j]; fs[2][j + 4] = b2[j];
        }
    }

    const float* cb = core + ((size_t)img * 300 + g * 75 + seg * 15) * HW_;

    f32x4 acc[3][3] = {};   // [c][slot]
#pragma unroll
    for (int k5 = 0; k5 < 5; ++k5) {      // dj = k5
#pragma unroll
        for (int c = 0; c < 3; ++c) {
            const float* pp = cb + (size_t)(k5 * 3 + c) * HW_;
            f32x4 d0 = *(const f32x4*)(pp + q0 * 4);
            f32x4 d1 = *(const f32x4*)(pp + q1 * 4);
            f32x4 d2 = *(const f32x4*)(pp + q2 * 4);
#pragma unroll
            for (int j = 0; j < 4; ++j) {
                acc[c][0][j] += d0[j] * fs[0][k5 + j];
                acc[c][1][j] += d1[j] * fs[1][k5 + j];
                acc[c][2][j] += d2[j] * fs[2][k5 + j];
            }
        }
    }

    float* pb = partial + (((size_t)img * 4 + g) * 5 + seg) * (3 * HW_);
#pragma unroll
    for (int c = 0; c < 3; ++c) {
        *(f32x4*)(pb + (size_t)c * HW_ + q0 * 4) = acc[c][0];
        *(f32x4*)(pb + (size_t)c * HW_ + q1 * 4) = acc[c][1];
        *(f32x4*)(pb + (size_t)c * HW_ + q2 * 4) = acc[c][2];
    }
}

// Kernel 3: combine: out_i[img][c][p] = 0.25 * sum_g kw[img][g][c][p] *
//                                        (sum_seg partial[img][g][seg][c][p])
__global__ void kcomb(const float* __restrict__ partial,
                      const float* __restrict__ kw,
                      float* __restrict__ outi) {
    int id = blockIdx.x * blockDim.x + threadIdx.x;   // thread per quad
    int img = id / (3 * (HW_ / 4));
    int r = id - img * (3 * (HW_ / 4));
    int c = r / (HW_ / 4);
    int q = r - c * (HW_ / 4);
    int p = q * 4;

    f32x4 o = {0.f, 0.f, 0.f, 0.f};
#pragma unroll
    for (int g = 0; g < 4; ++g) {
        f32x4 s = {0.f, 0.f, 0.f, 0.f};
#pragma unroll
        for (int seg = 0; seg < 5; ++seg) {
            f32x4 v = *(const f32x4*)(partial +
                (((size_t)img * 4 + g) * 5 + seg) * (3 * HW_) + (size_t)c * HW_ + p);
#pragma unroll
            for (int j = 0; j < 4; ++j) s[j] += v[j];
        }
        f32x4 kd = *(const f32x4*)(kw + ((size_t)img * 12 + g * 3 + c) * HW_ + p);
#pragma unroll
        for (int j = 0; j < 4; ++j) o[j] += kd[j] * s[j];
    }
#pragma unroll
    for (int j = 0; j < 4; ++j) o[j] *= 0.25f;
    *(f32x4*)(outi + ((size_t)img * 3 + c) * HW_ + p) = o;
}

// Kernel 4: pred_img[b,c,h,w] = mean over n of pred_img_i
__global__ void kmean(const float* __restrict__ outi, float* __restrict__ outm) {
    int id = blockIdx.x * blockDim.x + threadIdx.x;
    if (id >= B_ * 3 * HW_) return;
    int b = id / (3 * HW_);
    int rem = id - b * (3 * HW_);
    const float* p = outi + (size_t)b * (N_ * 3 * HW_) + rem;
    float s = 0.f;
#pragma unroll
    for (int n = 0; n < N_; ++n) s += p[(size_t)n * 3 * HW_];
    outm[id] = s * 0.125f;
}

extern "C" void kernel_launch(void* const* d_in, const int* in_sizes, int n_in,
                              void* d_out, int out_size, void* d_ws, size_t ws_size,
                              hipStream_t stream) {
    const float* frames = (const float*)d_in[0];   // [B,N,3,H,W]
    const float* core = (const float*)d_in[1];     // [B,N,300,H,W] (flat middle dims)
    const float* kw = (const float*)d_in[2];       // [B,N,4,3,H,W]
    float* cs = (float*)d_ws;                            // 128*2704 floats = 1.38 MB
    float* partial = cs + (size_t)IMGS_ * PHW_;          // 128*4*5*3*2304 = 70.8 MB
    float* outi = (float*)d_out;                         // pred_img_i: [B,N,3,H,W]
    float* outm = outi + (size_t)B_ * N_ * 3 * HW_;      // pred_img: [B,3,H,W]

    kcs<<<(IMGS_ * PHW_ + 255) / 256, 256, 0, stream>>>(frames, cs);
    kpart<<<IMGS_ * NK_ * 5, 192, 0, stream>>>(core, cs, partial);
    kcomb<<<(IMGS_ * 3 * (HW_ / 4)) / 256, 256, 0, stream>>>(partial, kw, outi);
    kmean<<<(B_ * 3 * HW_ + 255) / 256, 256, 0, stream>>>(outi, outm);
}

// Round 6
// 484.229 us; speedup vs baseline: 1.0348x; 1.0348x over previous
//
#include <hip/hip_runtime.h>
#include <stdint.h>
#include <stddef.h>

// Problem constants
constexpr int B_ = 16, N_ = 8, C_ = 3, H_ = 48, W_ = 48, K_ = 5, NK_ = 4;
constexpr int HW_ = H_ * W_;            // 2304
constexpr int IMGS_ = B_ * N_;          // 128
constexpr int PW_ = W_ + 4;             // 52 (padded width)
constexpr int PH_ = H_ + 4;             // 52
constexpr int PHW_ = PH_ * PW_;         // 2704
constexpr int CHUNKS_ = HW_ / 256;      // 9 chunks of 64 quads per image

typedef float f32x4 __attribute__((ext_vector_type(4)));

// Kernel 1: padded channel-sum of frames: cs[img][52][52] (fp32), zero border.
__global__ void kcs(const float* __restrict__ frames, float* __restrict__ cs) {
    int id = blockIdx.x * blockDim.x + threadIdx.x;
    if (id >= IMGS_ * PHW_) return;
    int img = id / PHW_;
    int rem = id - img * PHW_;
    int ph = rem / PW_;
    int pw = rem - ph * PW_;
    int h = ph - 2, w = pw - 2;
    float s = 0.f;
    if ((unsigned)h < (unsigned)H_ && (unsigned)w < (unsigned)W_) {
        const float* f = frames + (size_t)img * (C_ * HW_) + h * W_ + w;
        s = f[0] + f[HW_] + f[2 * HW_];
    }
    cs[id] = s;
}

// Kernel 2: main fused conv. Block = 256 threads = 4 waves; wave g computes
// the partial kw[g,c] * sum_k core[g*75+k*3+c] * fs for 64 pixel-quads, then
// LDS-reduce over the 4 groups. Measured DRAM-saturated (R4/R5 delta fit:
// marginal traffic moves at ~7 TB/s; core stream = 354 MB ⇒ ~56 us floor).
__global__ __launch_bounds__(256) void kmain(const float* __restrict__ core,
                                             const float* __restrict__ kw,
                                             const float* __restrict__ cs,
                                             float* __restrict__ out) {
    __shared__ float red[12 * 4 * 64];   // [(g*3+c)*4+j][q]  = 12 KB

    int t = threadIdx.x;
    int q = t & 63;        // quad index within chunk
    int g = t >> 6;        // kernel-weight group = wave id
    int img = blockIdx.x / CHUNKS_;
    int chunk = blockIdx.x - img * CHUNKS_;
    int pix0 = chunk * 256 + q * 4;
    int h = pix0 / W_;
    int w0 = pix0 - h * W_;

    // 5x8 channel-sum tile (padded coords: rows h..h+4, cols w0..w0+7)
    float fs[5][8];
    const float* csp = cs + img * PHW_ + h * PW_ + w0;
#pragma unroll
    for (int rr = 0; rr < 5; ++rr) {
        f32x4 a = *(const f32x4*)(csp + rr * PW_);
        f32x4 b = *(const f32x4*)(csp + rr * PW_ + 4);
        fs[rr][0] = a.x; fs[rr][1] = a.y; fs[rr][2] = a.z; fs[rr][3] = a.w;
        fs[rr][4] = b.x; fs[rr][5] = b.y; fs[rr][6] = b.z; fs[rr][7] = b.w;
    }

    const float* cp = core + (size_t)img * (300 * HW_) + (size_t)(g * 75) * HW_ + pix0;
    const float* kp = kw + (size_t)img * (12 * HW_) + (size_t)(g * 3) * HW_ + pix0;

#pragma unroll
    for (int c = 0; c < 3; ++c) {
        float t0 = 0.f, t1 = 0.f, t2 = 0.f, t3 = 0.f;
#pragma unroll
        for (int k = 0; k < 25; ++k) {
            f32x4 d = *(const f32x4*)(cp + (size_t)(k * 3 + c) * HW_);
            int di = k / 5, dj = k - di * 5;
            t0 += d.x * fs[di][dj + 0];
            t1 += d.y * fs[di][dj + 1];
            t2 += d.z * fs[di][dj + 2];
            t3 += d.w * fs[di][dj + 3];
        }
        f32x4 kd = *(const f32x4*)(kp + (size_t)c * HW_);
        int base = ((g * 3 + c) * 4) * 64 + q;
        red[base + 0 * 64] = kd.x * t0;
        red[base + 1 * 64] = kd.y * t1;
        red[base + 2 * 64] = kd.z * t2;
        red[base + 3 * 64] = kd.w * t3;
    }

    __syncthreads();

    // Reduce over g: threads 0..191, thread (c, q') sums 4 groups for 4 pixels.
    if (t < 192) {
        int c = t >> 6;
        int qq = t & 63;
        f32x4 o;
#pragma unroll
        for (int j = 0; j < 4; ++j) {
            int base = (c * 4 + j) * 64 + qq;
            float s = red[base] + red[base + 3 * 4 * 64]
                    + red[base + 6 * 4 * 64] + red[base + 9 * 4 * 64];
            o[j] = 0.25f * s;
        }
        *(f32x4*)(out + (size_t)img * (3 * HW_) + (size_t)c * HW_ + chunk * 256 + qq * 4) = o;
    }
}

// Kernel 3: pred_img[b,c,h,w] = mean over n of pred_img_i
__global__ void kmean(const float* __restrict__ outi, float* __restrict__ outm) {
    int id = blockIdx.x * blockDim.x + threadIdx.x;
    if (id >= B_ * 3 * HW_) return;
    int b = id / (3 * HW_);
    int rem = id - b * (3 * HW_);
    const float* p = outi + (size_t)b * (N_ * 3 * HW_) + rem;
    float s = 0.f;
#pragma unroll
    for (int n = 0; n < N_; ++n) s += p[(size_t)n * 3 * HW_];
    outm[id] = s * 0.125f;
}

extern "C" void kernel_launch(void* const* d_in, const int* in_sizes, int n_in,
                              void* d_out, int out_size, void* d_ws, size_t ws_size,
                              hipStream_t stream) {
    const float* frames = (const float*)d_in[0];   // [B,N,3,H,W]
    const float* core = (const float*)d_in[1];     // [B,N,300,H,W] (flat middle dims)
    const float* kw = (const float*)d_in[2];       // [B,N,4,3,H,W]
    float* cs = (float*)d_ws;                      // 128*52*52 fp32 = 1.38 MB
    float* outi = (float*)d_out;                   // pred_img_i: [B,N,3,H,W]
    float* outm = outi + (size_t)B_ * N_ * 3 * HW_; // pred_img: [B,3,H,W]

    kcs<<<(IMGS_ * PHW_ + 255) / 256, 256, 0, stream>>>(frames, cs);
    kmain<<<IMGS_ * CHUNKS_, 256, 0, stream>>>(core, kw, cs, outi);
    kmean<<<(B_ * 3 * HW_ + 255) / 256, 256, 0, stream>>>(outi, outm);
}